// Round 9
// baseline (428.044 us; speedup 1.0000x reference)
//
#include <hip/hip_runtime.h>
#include <math.h>

#define B_    64
#define W_    128
#define N_    40
#define FIN   66
#define HID   100
#define NEWD  71
#define MSEQ  10
#define NBLK  256
#define NTHR  1024  // 16 waves: 13 gate + 2 decay + 1 staging
#define E_    240

#define NGU   150   // gate units: 25 tiles * 6 kc
#define NU    178   // + decay units: 7 tiles * 4 kc (natural rows)

// hx row: 2 parity regions of 192 cols:
//   [0..99]=h  [100]=1(bias)  [101..103]=0  [104..167]=X cont  [168..174]=emb  [175..191]=0
#define HROW  392
// cx row: 2 parity regions of 128 cols: [0..99]=c [100]=1(bias) [101..127]=0
#define CROW  264
#define ROWH(m) ((m)*HROW + (((m)>>3)<<3))
#define ROWC(m) ((m)*CROW + (((m)>>3)<<3))
#define HXSZ  (15*HROW + 8 + HROW)
#define CXSZ  (15*CROW + 8 + CROW)

typedef float    f32x4 __attribute__((ext_vector_type(4)));
typedef _Float16 f16x4 __attribute__((ext_vector_type(4)));
typedef _Float16 f16x8 __attribute__((ext_vector_type(8)));

__device__ __forceinline__ float sig_(float x) {
    return __builtin_amdgcn_rcpf(1.0f + __expf(-x));
}
__device__ __forceinline__ float tanh_(float x) {
    return fmaf(2.0f, __builtin_amdgcn_rcpf(1.0f + __expf(-2.0f * x)), -1.0f);
}

// lgkm-only barrier: LDS visibility without draining global prefetch (vmcnt)
#define LBAR() do {                                            \
    asm volatile("s_waitcnt lgkmcnt(0)" ::: "memory");         \
    __builtin_amdgcn_s_barrier();                              \
    asm volatile("" ::: "memory");                             \
} while (0)

// ---------------------------------------------------------------------------
// Repack weights into f16 A-fragments for mfma_f32_16x16x32_f16.
// A-frag: lane l holds row R=l&15, k=(l>>4)*8+e.
// GATE (u<150): rows interleaved R=4*unit+gate -> src row gate*100+unit.
//   k<100: Wall; k==100: Wall_b+Uall_b; 104..167: Uall[0..63];
//   168..174: Uall[64..70]; else 0.
// DECAY (u>=150): natural rows R = Wd row (tile D covers rows 16D..16D+15).
//   k<100: Wd; k==100: Wd_b; else 0.
// ---------------------------------------------------------------------------
__global__ void repack_kernel(const float* __restrict__ Wall_w,
                              const float* __restrict__ Uall_w,
                              const float* __restrict__ Wd_w,
                              const float* __restrict__ Wall_b,
                              const float* __restrict__ Uall_b,
                              const float* __restrict__ Wd_b,
                              _Float16* __restrict__ Wfrag)
{
    int idx = blockIdx.x * 256 + threadIdx.x;
    if (idx >= NU * 64) return;
    int u = idx >> 6, l = idx & 63;
    f16x8 v;
    #pragma unroll
    for (int e = 0; e < 8; ++e) {
        float wv = 0.0f;
        int k = ((l >> 4) << 3) + e;
        if (u < NGU) {
            int T = u / 6, j = u % 6;
            int R = T * 16 + (l & 15);
            int src = (R & 3) * 100 + (R >> 2);
            k += j * 32;
            if (k < 100)                    wv = Wall_w[src * HID + k];
            else if (k == 100)              wv = Wall_b[src] + Uall_b[src];
            else if (k >= 104 && k < 168)   wv = Uall_w[src * NEWD + (k - 104)];
            else if (k >= 168 && k < 175)   wv = Uall_w[src * NEWD + 64 + (k - 168)];
        } else {
            int du = u - NGU;
            int D = du >> 2, j = du & 3;
            int R = D * 16 + (l & 15);
            k += j * 32;
            if (R < 100) {
                if (k < 100)       wv = Wd_w[R * HID + k];
                else if (k == 100) wv = Wd_b[R];
            }
        }
        v[e] = (_Float16)wv;
    }
    *(f16x8*)(Wfrag + (size_t)idx * 8) = v;
}

// ---------------------------------------------------------------------------
// LSTM: 256 blocks x 1024 threads (16 waves, 4/SIMD). TWO lgkm barriers/step.
// Waves 0..12 GATE: tiles {2wv, min(2wv+1,24)}.
// Waves 13..14 DECAY: natural tiles {0..3},{4..6}; preact f32x4 -> cs1_s,
//   GUARDED to rows < 100 (r8 bug: tile 6 rows 100..111 overflowed into the
//   next sequence's cs1 region at stride 100).
// Wave 15 STAGING: step w+1 LDS writes + step w+2 global loads.
// ---------------------------------------------------------------------------
__global__ __launch_bounds__(NTHR, 4)
void lstm_kernel(const float* __restrict__ X, const float* __restrict__ ts,
                 const float* __restrict__ emb_pos, const float* __restrict__ emb_team,
                 const _Float16* __restrict__ Wfrag,
                 const float* __restrict__ lin_w, const float* __restrict__ lin_b,
                 float* __restrict__ nodes)
{
    __shared__ __align__(16) _Float16 hx[HXSZ];
    __shared__ __align__(16) _Float16 cx[CXSZ];
    __shared__ __align__(16) float cs1_s[16 * 100];   // [m][row] preacts
    __shared__ float ts_s[2][16];

    const int t = threadIdx.x, l = t & 63, wv = t >> 6;
    const int uoff = l >> 4, m = l & 15;
    const int r0 = blockIdx.x * MSEQ;

    // ---- zero LDS ----
    for (int i = t; i < HXSZ; i += NTHR) hx[i] = (_Float16)0.0f;
    for (int i = t; i < CXSZ; i += NTHR) cx[i] = (_Float16)0.0f;
    if (t < 32) ((float*)ts_s)[t] = 0.0f;

    // ---- gate-wave config (wv < 13) ----
    const int tA = (2 * wv < 25) ? 2 * wv : 24;
    const int tB = (2 * wv + 1 < 25) ? (2 * wv + 1) : 24;
    const int uA = 4 * tA + uoff, uB = 4 * tB + uoff;
    f16x8 afA[6], afB[6];
    if (wv < 13) {
        #pragma unroll
        for (int j = 0; j < 6; ++j) {
            afA[j] = *(const f16x8*)(Wfrag + ((size_t)(tA * 6 + j) * 64 + l) * 8);
            afB[j] = *(const f16x8*)(Wfrag + ((size_t)(tB * 6 + j) * 64 + l) * 8);
        }
    }
    float cregA = 0.f, cregB = 0.f;

    // ---- decay-wave config (wv == 13, 14) ----
    const int dbase = (wv == 13) ? 0 : 4;
    const int nD    = (wv == 13) ? 4 : 3;
    f16x8 ad[4][4];
    if (wv == 13 || wv == 14) {
        #pragma unroll
        for (int i = 0; i < 4; ++i)
            if (i < nD) {
                #pragma unroll
                for (int j = 0; j < 4; ++j)
                    ad[i][j] = *(const f16x8*)(Wfrag + ((size_t)(NGU + (dbase + i) * 4 + j) * 64 + l) * 8);
            }
    }

    // ---- staging roles (wave 15) ----
    const float* xld = nullptr; int xm = 0, xq = 0;
    const float* xcat = nullptr; int me = 0;
    const float* tsp = nullptr; int mt = 0;
    if (wv == 15) {
        if (l < 40) {
            xm = l >> 2; xq = l & 3;
            int r = r0 + xm, b = r / N_, n = r % N_;
            xld = X + ((size_t)b * W_ * N_ + n) * FIN + 16 * xq;
        } else if (l < 50) {
            me = l - 40;
            int r = r0 + me, b = r / N_, n = r % N_;
            xcat = X + ((size_t)b * W_ * N_ + n) * FIN;
        } else if (l < 60) {
            mt = l - 50;
            int r = r0 + mt, b = r / N_, n = r % N_;
            tsp = ts + (size_t)b * W_ * N_ + n;
        }
    }
    __syncthreads();

    // ---- constant-1 bias inputs (both parities) ----
    if (t < 32) {
        int r = t & 15, pp = t >> 4;
        hx[ROWH(r) + pp * 192 + 100] = (_Float16)1.0f;
        cx[ROWC(r) + pp * 128 + 100] = (_Float16)1.0f;
    }
    // ---- stage xe(0)/ts(0) into parity 0 ----
    if (xld) {
        float4 a0 = *(const float4*)(xld + 0);
        float4 a1 = *(const float4*)(xld + 4);
        float4 a2 = *(const float4*)(xld + 8);
        float4 a3 = *(const float4*)(xld + 12);
        f16x8 v0 = {(_Float16)a0.x,(_Float16)a0.y,(_Float16)a0.z,(_Float16)a0.w,
                    (_Float16)a1.x,(_Float16)a1.y,(_Float16)a1.z,(_Float16)a1.w};
        f16x8 v1 = {(_Float16)a2.x,(_Float16)a2.y,(_Float16)a2.z,(_Float16)a2.w,
                    (_Float16)a3.x,(_Float16)a3.y,(_Float16)a3.z,(_Float16)a3.w};
        *(f16x8*)&hx[ROWH(xm) + 104 + 16 * xq]     = v0;
        *(f16x8*)&hx[ROWH(xm) + 104 + 16 * xq + 8] = v1;
    }
    if (xcat) {
        float c0f = xcat[64], c1f = xcat[65];
        int ip = (int)c0f, itm = (int)c1f;
        int sp = ip > 0 ? ip - 1 : 0;   float fp  = ip > 0 ? 1.f : 0.f;
        int st = itm > 0 ? itm - 1 : 0; float ft_ = itm > 0 ? 1.f : 0.f;
        #pragma unroll
        for (int q = 0; q < 4; ++q) hx[ROWH(me) + 168 + q] = (_Float16)(emb_pos[sp * 4 + q] * fp);
        #pragma unroll
        for (int q = 0; q < 3; ++q) hx[ROWH(me) + 172 + q] = (_Float16)(emb_team[st * 3 + q] * ft_);
    }
    if (tsp) ts_s[0][mt] = tsp[0];

    // ---- preload regs for step 1 ----
    float4 px0 = {0,0,0,0}, px1 = {0,0,0,0}, px2 = {0,0,0,0}, px3 = {0,0,0,0};
    float pc0 = 0.f, pc1 = 0.f, ptv = 0.f;
    {
        const size_t off1 = (size_t)N_ * FIN;
        if (xld) {
            px0 = *(const float4*)(xld + off1 + 0);
            px1 = *(const float4*)(xld + off1 + 4);
            px2 = *(const float4*)(xld + off1 + 8);
            px3 = *(const float4*)(xld + off1 + 12);
        }
        if (xcat) { pc0 = xcat[off1 + 64]; pc1 = xcat[off1 + 65]; }
        if (tsp)  ptv = tsp[(size_t)N_];
    }
    __syncthreads();

    const int rowhm = ROWH(m) + (uoff << 3);
    const int rowcm = ROWC(m) + (uoff << 3);
    const int rowhw = ROWH(m);
    const int rowcw = ROWC(m);

    // ---- main loop: 2 lgkm barriers per step ----
    for (int w = 0; w < W_; ++w) {
        const int p = w & 1, np = p ^ 1;
        f32x4 aG0 = {0.f,0.f,0.f,0.f}, aG1 = {0.f,0.f,0.f,0.f};

        if (wv < 13) {
            // ===== GATE phase 1: bh reads + 12 MFMA =====
            const int hb = rowhm + p * 192;
            #pragma unroll
            for (int j = 0; j < 6; ++j) {
                f16x8 bb = *(const f16x8*)&hx[hb + j * 32];
                aG0 = __builtin_amdgcn_mfma_f32_16x16x32_f16(afA[j], bb, aG0, 0, 0, 0);
                aG1 = __builtin_amdgcn_mfma_f32_16x16x32_f16(afB[j], bb, aG1, 0, 0, 0);
            }
        } else if (wv < 15) {
            // ===== DECAY phase 1: bc reads + MFMA + guarded preact writes =====
            f32x4 aD[4];
            #pragma unroll
            for (int i = 0; i < 4; ++i) aD[i] = (f32x4){0.f,0.f,0.f,0.f};
            const int cb = rowcm + p * 128;
            #pragma unroll
            for (int j = 0; j < 4; ++j) {
                f16x8 bc = *(const f16x8*)&cx[cb + j * 32];
                #pragma unroll
                for (int i = 0; i < 4; ++i)
                    if (i < nD)
                        aD[i] = __builtin_amdgcn_mfma_f32_16x16x32_f16(ad[i][j], bc, aD[i], 0, 0, 0);
            }
            #pragma unroll
            for (int i = 0; i < 4; ++i)
                if (i < nD) {
                    const int rb = (dbase + i) * 16 + 4 * uoff;
                    if (rb < 100)   // r8 bug fix: tile 6 rows 100..111 are pad
                        *(f32x4*)&cs1_s[100 * m + rb] = aD[i];
                }
        } else {
            // ===== STAGING phase 1: write step w+1, issue loads w+2 =====
            if (w + 1 < W_) {
                if (xld) {
                    f16x8 v0 = {(_Float16)px0.x,(_Float16)px0.y,(_Float16)px0.z,(_Float16)px0.w,
                                (_Float16)px1.x,(_Float16)px1.y,(_Float16)px1.z,(_Float16)px1.w};
                    f16x8 v1 = {(_Float16)px2.x,(_Float16)px2.y,(_Float16)px2.z,(_Float16)px2.w,
                                (_Float16)px3.x,(_Float16)px3.y,(_Float16)px3.z,(_Float16)px3.w};
                    *(f16x8*)&hx[ROWH(xm) + np * 192 + 104 + 16 * xq]     = v0;
                    *(f16x8*)&hx[ROWH(xm) + np * 192 + 104 + 16 * xq + 8] = v1;
                }
                if (xcat) {
                    int ip = (int)pc0, itm = (int)pc1;
                    int sp = ip > 0 ? ip - 1 : 0;   float fp  = ip > 0 ? 1.f : 0.f;
                    int st = itm > 0 ? itm - 1 : 0; float ft_ = itm > 0 ? 1.f : 0.f;
                    #pragma unroll
                    for (int q = 0; q < 4; ++q) hx[ROWH(me) + np * 192 + 168 + q] = (_Float16)(emb_pos[sp * 4 + q] * fp);
                    #pragma unroll
                    for (int q = 0; q < 3; ++q) hx[ROWH(me) + np * 192 + 172 + q] = (_Float16)(emb_team[st * 3 + q] * ft_);
                }
                if (tsp) ts_s[np][mt] = ptv;
                if (w + 2 < W_) {
                    const size_t off = (size_t)(w + 2) * (N_ * FIN);
                    if (xld) {
                        px0 = *(const float4*)(xld + off + 0);
                        px1 = *(const float4*)(xld + off + 4);
                        px2 = *(const float4*)(xld + off + 8);
                        px3 = *(const float4*)(xld + off + 12);
                    }
                    if (xcat) { pc0 = xcat[off + 64]; pc1 = xcat[off + 65]; }
                    if (tsp)  ptv = tsp[(size_t)(w + 2) * N_];
                }
            }
        }
        LBAR();   // mid-step: cs1 preacts + xe(w+1) visible

        // ===== phase 2: gate update (in-register) =====
        if (wv < 13 && m < MSEQ) {
            const float tsv = ts_s[p][m];
            const float e1 = tsv - 1.0f;
            {
                float cs1 = tanh_(cs1_s[100 * m + uA]);
                float cn = sig_(aG0[0]) * fmaf(cs1, e1, cregA) + sig_(aG0[1]) * sig_(aG0[3]);
                cregA = cn;
                hx[rowhw + np * 192 + uA] = (_Float16)(sig_(aG0[2]) * tanh_(cn));
                cx[rowcw + np * 128 + uA] = (_Float16)cn;
            }
            {
                float cs1 = tanh_(cs1_s[100 * m + uB]);
                float cn = sig_(aG1[0]) * fmaf(cs1, e1, cregB) + sig_(aG1[1]) * sig_(aG1[3]);
                cregB = cn;
                hx[rowhw + np * 192 + uB] = (_Float16)(sig_(aG1[2]) * tanh_(cn));
                cx[rowcw + np * 128 + uB] = (_Float16)cn;
            }
        }
        LBAR();   // end-of-step: h/c(np) visible
    }

    // ---- lin head: final h is in parity 0 ----
    if (t < HID * MSEQ) {
        const int i = t / MSEQ, mm = t % MSEQ;
        const float* lr = lin_w + (size_t)i * HID;
        float acc2 = lin_b[i];
        for (int k = 0; k < HID; ++k)
            acc2 = fmaf(lr[k], (float)hx[ROWH(mm) + k], acc2);
        nodes[(size_t)(r0 + mm) * HID + i] = fmaxf(acc2, 0.0f);
    }
}

// ---------------------------------------------------------------------------
// Kernel B: per-batch GraphSAGE x2 + head. (r7 version — validated fast)
// ---------------------------------------------------------------------------
__global__ __launch_bounds__(512, 1)
void sage_kernel(const float* __restrict__ nodes, const int* __restrict__ edge,
                 const float* __restrict__ s1l, const float* __restrict__ s1lb,
                 const float* __restrict__ s1r,
                 const float* __restrict__ s2l, const float* __restrict__ s2lb,
                 const float* __restrict__ s2r,
                 const float* __restrict__ ow,  const float* __restrict__ ob,
                 float* __restrict__ out)
{
    __shared__ float nd[N_ * HID];
    __shared__ float agg[N_ * HID];
    __shared__ float g1[N_ * 64];
    __shared__ float agg2[N_ * 64];
    __shared__ float g2[N_ * 32];
    __shared__ float deg[N_];
    __shared__ float invdeg[N_];

    const int t = threadIdx.x;
    const int b = blockIdx.x;
    const int* esrc = edge;
    const int* edst = edge + E_;

    for (int i = t; i < N_ * HID; i += 512) {
        nd[i]  = nodes[(size_t)b * N_ * HID + i];
        agg[i] = 0.0f;
    }
    for (int i = t; i < N_; i += 512) deg[i] = 0.0f;
    __syncthreads();

    if (t < E_) atomicAdd(&deg[edst[t]], 1.0f);
    for (int i = t; i < E_ * HID; i += 512) {
        int e = i / HID, k = i % HID;
        atomicAdd(&agg[edst[e] * HID + k], nd[esrc[e] * HID + k]);
    }
    __syncthreads();
    for (int i = t; i < N_; i += 512) invdeg[i] = 1.0f / fmaxf(deg[i], 1.0f);
    __syncthreads();

    {
        const int i = t >> 3, n0 = t & 7;
        const float4* lr = (const float4*)(s1l + (size_t)i * HID);
        const float4* rr = (const float4*)(s1r + (size_t)i * HID);
        float acc[5], id[5];
        #pragma unroll
        for (int j = 0; j < 5; ++j) {
            acc[j] = s1lb[i];
            id[j]  = invdeg[n0 + 8 * j];
        }
        for (int kq = 0; kq < 25; ++kq) {
            float4 lw = lr[kq], rw = rr[kq];
            #pragma unroll
            for (int j = 0; j < 5; ++j) {
                const int n = n0 + 8 * j;
                float4 ag = *(const float4*)&agg[n * HID + 4 * kq];
                float4 nv = *(const float4*)&nd[n * HID + 4 * kq];
                acc[j] = fmaf(lw.x, ag.x * id[j], acc[j]);
                acc[j] = fmaf(lw.y, ag.y * id[j], acc[j]);
                acc[j] = fmaf(lw.z, ag.z * id[j], acc[j]);
                acc[j] = fmaf(lw.w, ag.w * id[j], acc[j]);
                acc[j] = fmaf(rw.x, nv.x, acc[j]);
                acc[j] = fmaf(rw.y, nv.y, acc[j]);
                acc[j] = fmaf(rw.z, nv.z, acc[j]);
                acc[j] = fmaf(rw.w, nv.w, acc[j]);
            }
        }
        #pragma unroll
        for (int j = 0; j < 5; ++j)
            g1[(n0 + 8 * j) * 64 + i] = fmaxf(acc[j], 0.0f);
    }
    __syncthreads();
    for (int i = t; i < N_ * 64; i += 512) agg2[i] = 0.0f;
    __syncthreads();
    for (int i = t; i < E_ * 64; i += 512) {
        int e = i >> 6, k = i & 63;
        atomicAdd(&agg2[edst[e] * 64 + k], g1[esrc[e] * 64 + k]);
    }
    __syncthreads();

    {
        const int i = t >> 4, n0 = t & 15;
        const float4* lr = (const float4*)(s2l + (size_t)i * 64);
        const float4* rr = (const float4*)(s2r + (size_t)i * 64);
        float acc[3] = {s2lb[i], s2lb[i], s2lb[i]};
        float id[3];
        #pragma unroll
        for (int j = 0; j < 3; ++j) {
            int n = n0 + 16 * j;
            id[j] = (n < N_) ? invdeg[n] : 0.0f;
        }
        for (int kq = 0; kq < 16; ++kq) {
            float4 lw = lr[kq], rw = rr[kq];
            #pragma unroll
            for (int j = 0; j < 3; ++j) {
                const int n = n0 + 16 * j;
                if (n < N_) {
                    float4 ag = *(const float4*)&agg2[n * 64 + 4 * kq];
                    float4 nv = *(const float4*)&g1[n * 64 + 4 * kq];
                    acc[j] = fmaf(lw.x, ag.x * id[j], acc[j]);
                    acc[j] = fmaf(lw.y, ag.y * id[j], acc[j]);
                    acc[j] = fmaf(lw.z, ag.z * id[j], acc[j]);
                    acc[j] = fmaf(lw.w, ag.w * id[j], acc[j]);
                    acc[j] = fmaf(rw.x, nv.x, acc[j]);
                    acc[j] = fmaf(rw.y, nv.y, acc[j]);
                    acc[j] = fmaf(rw.z, nv.z, acc[j]);
                    acc[j] = fmaf(rw.w, nv.w, acc[j]);
                }
            }
        }
        #pragma unroll
        for (int j = 0; j < 3; ++j) {
            int n = n0 + 16 * j;
            if (n < N_) g2[n * 32 + i] = fmaxf(acc[j], 0.0f);
        }
    }
    __syncthreads();

    if (t < N_ * 2) {
        const int n = t >> 1, c = t & 1;
        const float4* wr = (const float4*)(ow + (size_t)c * 32);
        float acc = ob[c];
        for (int kq = 0; kq < 8; ++kq) {
            float4 w4 = wr[kq];
            float4 g4 = *(const float4*)&g2[n * 32 + 4 * kq];
            acc = fmaf(w4.x, g4.x, acc);
            acc = fmaf(w4.y, g4.y, acc);
            acc = fmaf(w4.z, g4.z, acc);
            acc = fmaf(w4.w, g4.w, acc);
        }
        out[((size_t)b * N_ + n) * 2 + c] = fmaxf(acc, 0.0f);
    }
}

extern "C" void kernel_launch(void* const* d_in, const int* in_sizes, int n_in,
                              void* d_out, int out_size, void* d_ws, size_t ws_size,
                              hipStream_t stream) {
    const float* X        = (const float*)d_in[0];
    const float* ts       = (const float*)d_in[1];
    const int*   edge     = (const int*)  d_in[2];
    const float* emb_pos  = (const float*)d_in[3];
    const float* emb_team = (const float*)d_in[4];
    const float* Wall_w   = (const float*)d_in[5];
    const float* Wall_b   = (const float*)d_in[6];
    const float* Uall_w   = (const float*)d_in[7];
    const float* Uall_b   = (const float*)d_in[8];
    const float* Wd_w     = (const float*)d_in[9];
    const float* Wd_b     = (const float*)d_in[10];
    const float* lin_w    = (const float*)d_in[11];
    const float* lin_b    = (const float*)d_in[12];
    const float* s1l      = (const float*)d_in[13];
    const float* s1lb     = (const float*)d_in[14];
    const float* s1r      = (const float*)d_in[15];
    const float* s2l      = (const float*)d_in[16];
    const float* s2lb     = (const float*)d_in[17];
    const float* s2r      = (const float*)d_in[18];
    const float* ow       = (const float*)d_in[19];
    const float* ob       = (const float*)d_in[20];

    float*     nodes = (float*)d_ws;                              // 1,024,000 B
    _Float16*  Wfrag = (_Float16*)((char*)d_ws + 1024000);        // 178*64*8*2 = 182,272 B

    repack_kernel<<<(NU * 64 + 255) / 256, 256, 0, stream>>>(Wall_w, Uall_w, Wd_w,
                                                             Wall_b, Uall_b, Wd_b, Wfrag);

    lstm_kernel<<<NBLK, NTHR, 0, stream>>>(X, ts, emb_pos, emb_team, Wfrag,
                                           lin_w, lin_b, nodes);
    sage_kernel<<<B_, 512, 0, stream>>>(nodes, edge, s1l, s1lb, s1r,
                                        s2l, s2lb, s2r, ow, ob, (float*)d_out);
}

// Round 10
// 260.909 us; speedup vs baseline: 1.6406x; 1.6406x over previous
//
#include <hip/hip_runtime.h>
#include <math.h>

#define B_    64
#define W_    128
#define N_    40
#define FIN   66
#define HID   100
#define NEWD  71
#define MSEQ  10
#define NBLK  256
#define NTHR  1024  // 16 waves: 13 compute + 3 staging
#define E_    240

#define NGU   150   // gate units: 25 tiles * 6 kc
#define NDU   100   // decay-mini units: 25 tiles * 4 kc (rows duplicated x4)
#define NU    250

// hx row: 2 parity regions of 192 cols ([0..99]=h [100..170]=xe [171]=1 [172..191]=0)
#define HROW  392
#define CROW  264   // cx row: 2 parity regions of 128 ([0..99]=c [100]=1 [101..127]=0)
#define ROWH(m) ((m)*HROW + (((m)>>3)<<3))
#define ROWC(m) ((m)*CROW + (((m)>>3)<<3))
#define HXSZ  (15*HROW + 8 + HROW)   // 6280
#define CXSZ  (15*CROW + 8 + CROW)   // 4232

typedef float    f32x4 __attribute__((ext_vector_type(4)));
typedef _Float16 f16x4 __attribute__((ext_vector_type(4)));
typedef _Float16 f16x8 __attribute__((ext_vector_type(8)));

__device__ __forceinline__ float sig_(float x) {
    return __builtin_amdgcn_rcpf(1.0f + __expf(-x));
}
__device__ __forceinline__ float tanh_(float x) {
    return fmaf(2.0f, __builtin_amdgcn_rcpf(1.0f + __expf(-2.0f * x)), -1.0f);
}

// lgkm-only barrier: LDS visibility without draining global prefetch (vmcnt)
#define LBAR() do {                                            \
    asm volatile("s_waitcnt lgkmcnt(0)" ::: "memory");         \
    __builtin_amdgcn_s_barrier();                              \
    asm volatile("" ::: "memory");                             \
} while (0)

// ---------------------------------------------------------------------------
// Repack weights into f16 A-fragments for mfma_f32_16x16x32_f16 (r6 layout,
// validated: absmax 2.44e-4 at 197us).
// GATE (u<150): rows interleaved R=4*unit+gate -> src row gate*100+unit.
//   k<100: Wall; 100..170: Uall; k==171: Wall_b+Uall_b (bias-as-input); else 0.
// DECAY-MINI (u>=150): row R -> Wd row 4T+(R>>2) (4x duplicated rows).
//   k<100: Wd; k==100: Wd_b; else 0.
// ---------------------------------------------------------------------------
__global__ void repack_kernel(const float* __restrict__ Wall_w,
                              const float* __restrict__ Uall_w,
                              const float* __restrict__ Wd_w,
                              const float* __restrict__ Wall_b,
                              const float* __restrict__ Uall_b,
                              const float* __restrict__ Wd_b,
                              _Float16* __restrict__ Wfrag)
{
    int idx = blockIdx.x * 256 + threadIdx.x;
    if (idx >= NU * 64) return;
    int u = idx >> 6, l = idx & 63;
    f16x8 v;
    #pragma unroll
    for (int e = 0; e < 8; ++e) {
        float wv = 0.0f;
        int k = ((l >> 4) << 3) + e;
        if (u < NGU) {
            int T = u / 6, j = u % 6;
            int R = T * 16 + (l & 15);
            int src = (R & 3) * 100 + (R >> 2);
            k += j * 32;
            if (k < 100)       wv = Wall_w[src * HID + k];
            else if (k < 171)  wv = Uall_w[src * NEWD + (k - 100)];
            else if (k == 171) wv = Wall_b[src] + Uall_b[src];
        } else {
            int du = u - NGU;
            int T = du >> 2, j = du & 3;
            int srcrow = 4 * T + ((l & 15) >> 2);
            k += j * 32;
            if (k < 100)       wv = Wd_w[srcrow * HID + k];
            else if (k == 100) wv = Wd_b[srcrow];
        }
        v[e] = (_Float16)wv;
    }
    *(f16x8*)(Wfrag + (size_t)idx * 8) = v;
}

// ---------------------------------------------------------------------------
// LSTM: 256 blocks x 1024 threads. ONE lgkm barrier per step. (r6 verbatim —
// measured 197us, the best of r3..r9; r7/r9 restructures both regressed.)
// Waves 0..12 compute: slots tA=2wv, tB=min(2wv+1,24).
//   Per step: 6 bh + 4 bc b128 reads (parity p), 12 gate + 8 decay-mini MFMA,
//   sigmoid/tanh + c/h update fully in-register, write h/c f16 to parity p^1.
// Waves 13..15 staging: write xe(w+1)/ts(w+1) from regs preloaded one step
//   earlier (global loads never drained: LBAR has no vmcnt).
// ---------------------------------------------------------------------------
__global__ __launch_bounds__(NTHR, 4)
void lstm_kernel(const float* __restrict__ X, const float* __restrict__ ts,
                 const float* __restrict__ emb_pos, const float* __restrict__ emb_team,
                 const _Float16* __restrict__ Wfrag,
                 const float* __restrict__ lin_w, const float* __restrict__ lin_b,
                 float* __restrict__ nodes)
{
    __shared__ __align__(16) _Float16 hx[HXSZ];
    __shared__ __align__(16) _Float16 cx[CXSZ];
    __shared__ float ts_s[2][16];

    const int t = threadIdx.x, l = t & 63, wv = t >> 6;
    const int uoff = l >> 4, m = l & 15;
    const int r0 = blockIdx.x * MSEQ;
    const bool comp = (wv < 13);

    // ---- zero LDS ----
    for (int i = t; i < HXSZ; i += NTHR) hx[i] = (_Float16)0.0f;
    for (int i = t; i < CXSZ; i += NTHR) cx[i] = (_Float16)0.0f;
    if (t < 32) ((float*)ts_s)[t] = 0.0f;

    // ---- compute-wave setup ----
    const int tA = 2 * wv;
    const int tB = (2 * wv + 1 < 25) ? (2 * wv + 1) : 24;
    const int uA = 4 * tA + uoff, uB = 4 * tB + uoff;
    f16x8 afA[6], afB[6], adA[4], adB[4];
    if (comp) {
        #pragma unroll
        for (int j = 0; j < 6; ++j) {
            afA[j] = *(const f16x8*)(Wfrag + ((size_t)(tA * 6 + j) * 64 + l) * 8);
            afB[j] = *(const f16x8*)(Wfrag + ((size_t)(tB * 6 + j) * 64 + l) * 8);
        }
        #pragma unroll
        for (int j = 0; j < 4; ++j) {
            adA[j] = *(const f16x8*)(Wfrag + ((size_t)(NGU + tA * 4 + j) * 64 + l) * 8);
            adB[j] = *(const f16x8*)(Wfrag + ((size_t)(NGU + tB * 4 + j) * 64 + l) * 8);
        }
    }
    float cregA = 0.f, cregB = 0.f;

    // ---- staging roles (waves 13..15) ----
    const float* xld = nullptr; int xm = 0, xp = 0;
    const float* xcat = nullptr; int me = 0;
    const float* tsp = nullptr; int mt = 0;
    {
        int s = t - 832;
        if (s >= 0 && s < 160) {
            xm = s >> 4; xp = s & 15;
            int r = r0 + xm, b = r / N_, n = r % N_;
            xld = X + ((size_t)b * W_ * N_ + n) * FIN + 4 * xp;
        } else if (s >= 160 && s < 170) {
            me = s - 160;
            int r = r0 + me, b = r / N_, n = r % N_;
            xcat = X + ((size_t)b * W_ * N_ + n) * FIN;
        } else if (s >= 170 && s < 180) {
            mt = s - 170;
            int r = r0 + mt, b = r / N_, n = r % N_;
            tsp = ts + (size_t)b * W_ * N_ + n;
        }
    }
    __syncthreads();

    // ---- constant-1 bias inputs (both parities) ----
    if (t < 32) {
        int r = t & 15, pp = t >> 4;
        hx[ROWH(r) + pp * 192 + 171] = (_Float16)1.0f;
        cx[ROWC(r) + pp * 128 + 100] = (_Float16)1.0f;
    }
    // ---- stage xe(0)/ts(0) into parity 0 ----
    if (xld) {
        float2 a = *(const float2*)xld;
        float2 b2 = *(const float2*)(xld + 2);
        f16x4 v = {(_Float16)a.x, (_Float16)a.y, (_Float16)b2.x, (_Float16)b2.y};
        *(f16x4*)&hx[ROWH(xm) + 100 + 4 * xp] = v;
    }
    if (xcat) {
        float c0f = xcat[64], c1f = xcat[65];
        int ip = (int)c0f, itm = (int)c1f;
        int sp = ip > 0 ? ip - 1 : 0;   float fp  = ip > 0 ? 1.f : 0.f;
        int st = itm > 0 ? itm - 1 : 0; float ft_ = itm > 0 ? 1.f : 0.f;
        #pragma unroll
        for (int q = 0; q < 4; ++q) hx[ROWH(me) + 164 + q] = (_Float16)(emb_pos[sp * 4 + q] * fp);
        #pragma unroll
        for (int q = 0; q < 3; ++q) hx[ROWH(me) + 168 + q] = (_Float16)(emb_team[st * 3 + q] * ft_);
    }
    if (tsp) ts_s[0][mt] = tsp[0];

    // ---- preload regs for step 1 ----
    float2 pa = {0.f, 0.f}, pb = {0.f, 0.f};
    float pc0 = 0.f, pc1 = 0.f, ptv = 0.f;
    {
        const size_t off1 = (size_t)N_ * FIN;
        if (xld)  { pa = *(const float2*)(xld + off1); pb = *(const float2*)(xld + off1 + 2); }
        if (xcat) { pc0 = xcat[off1 + 64]; pc1 = xcat[off1 + 65]; }
        if (tsp)  ptv = tsp[(size_t)N_];
    }
    __syncthreads();

    const int rowhm = ROWH(m) + (uoff << 3);
    const int rowcm = ROWC(m) + (uoff << 3);
    const int rowhw = ROWH(m);
    const int rowcw = ROWC(m);

    // ---- main loop: ONE barrier per step ----
    for (int w = 0; w < W_; ++w) {
        const int p = w & 1, np = p ^ 1;
        if (comp) {
            const int hb = rowhm + p * 192;
            f16x8 bh0 = *(const f16x8*)&hx[hb];
            f16x8 bh1 = *(const f16x8*)&hx[hb + 32];
            f16x8 bh2 = *(const f16x8*)&hx[hb + 64];
            f16x8 bh3 = *(const f16x8*)&hx[hb + 96];
            f16x8 bh4 = *(const f16x8*)&hx[hb + 128];
            f16x8 bh5 = *(const f16x8*)&hx[hb + 160];
            f32x4 aA = {0.f, 0.f, 0.f, 0.f}, aB = {0.f, 0.f, 0.f, 0.f};
            aA = __builtin_amdgcn_mfma_f32_16x16x32_f16(afA[0], bh0, aA, 0, 0, 0);
            aB = __builtin_amdgcn_mfma_f32_16x16x32_f16(afB[0], bh0, aB, 0, 0, 0);
            aA = __builtin_amdgcn_mfma_f32_16x16x32_f16(afA[1], bh1, aA, 0, 0, 0);
            aB = __builtin_amdgcn_mfma_f32_16x16x32_f16(afB[1], bh1, aB, 0, 0, 0);
            aA = __builtin_amdgcn_mfma_f32_16x16x32_f16(afA[2], bh2, aA, 0, 0, 0);
            aB = __builtin_amdgcn_mfma_f32_16x16x32_f16(afB[2], bh2, aB, 0, 0, 0);
            aA = __builtin_amdgcn_mfma_f32_16x16x32_f16(afA[3], bh3, aA, 0, 0, 0);
            aB = __builtin_amdgcn_mfma_f32_16x16x32_f16(afB[3], bh3, aB, 0, 0, 0);
            aA = __builtin_amdgcn_mfma_f32_16x16x32_f16(afA[4], bh4, aA, 0, 0, 0);
            aB = __builtin_amdgcn_mfma_f32_16x16x32_f16(afB[4], bh4, aB, 0, 0, 0);
            aA = __builtin_amdgcn_mfma_f32_16x16x32_f16(afA[5], bh5, aA, 0, 0, 0);
            aB = __builtin_amdgcn_mfma_f32_16x16x32_f16(afB[5], bh5, aB, 0, 0, 0);

            const int cb = rowcm + p * 128;
            f16x8 bc0 = *(const f16x8*)&cx[cb];
            f16x8 bc1 = *(const f16x8*)&cx[cb + 32];
            f16x8 bc2 = *(const f16x8*)&cx[cb + 64];
            f16x8 bc3 = *(const f16x8*)&cx[cb + 96];
            f32x4 dA = {0.f, 0.f, 0.f, 0.f}, dB = {0.f, 0.f, 0.f, 0.f};
            dA = __builtin_amdgcn_mfma_f32_16x16x32_f16(adA[0], bc0, dA, 0, 0, 0);
            dB = __builtin_amdgcn_mfma_f32_16x16x32_f16(adB[0], bc0, dB, 0, 0, 0);
            dA = __builtin_amdgcn_mfma_f32_16x16x32_f16(adA[1], bc1, dA, 0, 0, 0);
            dB = __builtin_amdgcn_mfma_f32_16x16x32_f16(adB[1], bc1, dB, 0, 0, 0);
            dA = __builtin_amdgcn_mfma_f32_16x16x32_f16(adA[2], bc2, dA, 0, 0, 0);
            dB = __builtin_amdgcn_mfma_f32_16x16x32_f16(adB[2], bc2, dB, 0, 0, 0);
            dA = __builtin_amdgcn_mfma_f32_16x16x32_f16(adA[3], bc3, dA, 0, 0, 0);
            dB = __builtin_amdgcn_mfma_f32_16x16x32_f16(adB[3], bc3, dB, 0, 0, 0);

            if (m < MSEQ) {
                float tsv = ts_s[p][m];
                float e1 = tsv - 1.0f;
                float cs1A = tanh_(dA[0]);
                float cnA = sig_(aA[0]) * fmaf(cs1A, e1, cregA) + sig_(aA[1]) * sig_(aA[3]);
                cregA = cnA;
                hx[rowhw + np * 192 + uA] = (_Float16)(sig_(aA[2]) * tanh_(cnA));
                cx[rowcw + np * 128 + uA] = (_Float16)cnA;
                float cs1B = tanh_(dB[0]);
                float cnB = sig_(aB[0]) * fmaf(cs1B, e1, cregB) + sig_(aB[1]) * sig_(aB[3]);
                cregB = cnB;
                hx[rowhw + np * 192 + uB] = (_Float16)(sig_(aB[2]) * tanh_(cnB));
                cx[rowcw + np * 128 + uB] = (_Float16)cnB;
            }
        } else {
            if (w + 1 < W_) {
                if (xld) {
                    f16x4 v = {(_Float16)pa.x, (_Float16)pa.y, (_Float16)pb.x, (_Float16)pb.y};
                    *(f16x4*)&hx[ROWH(xm) + np * 192 + 100 + 4 * xp] = v;
                }
                if (xcat) {
                    int ip = (int)pc0, itm = (int)pc1;
                    int sp = ip > 0 ? ip - 1 : 0;   float fp  = ip > 0 ? 1.f : 0.f;
                    int st = itm > 0 ? itm - 1 : 0; float ft_ = itm > 0 ? 1.f : 0.f;
                    #pragma unroll
                    for (int q = 0; q < 4; ++q) hx[ROWH(me) + np * 192 + 164 + q] = (_Float16)(emb_pos[sp * 4 + q] * fp);
                    #pragma unroll
                    for (int q = 0; q < 3; ++q) hx[ROWH(me) + np * 192 + 168 + q] = (_Float16)(emb_team[st * 3 + q] * ft_);
                }
                if (tsp) ts_s[np][mt] = ptv;
                if (w + 2 < W_) {
                    const size_t off = (size_t)(w + 2) * (N_ * FIN);
                    if (xld)  { pa = *(const float2*)(xld + off); pb = *(const float2*)(xld + off + 2); }
                    if (xcat) { pc0 = xcat[off + 64]; pc1 = xcat[off + 65]; }
                    if (tsp)  ptv = tsp[(size_t)(w + 2) * N_];
                }
            }
        }
        LBAR();
    }

    // ---- lin head: final h is in parity 0 (written at w=127 -> np=0) ----
    if (t < HID * MSEQ) {
        const int i = t / MSEQ, mm = t % MSEQ;
        const float* lr = lin_w + (size_t)i * HID;
        float acc2 = lin_b[i];
        for (int k = 0; k < HID; ++k)
            acc2 = fmaf(lr[k], (float)hx[ROWH(mm) + k], acc2);
        nodes[(size_t)(r0 + mm) * HID + i] = fmaxf(acc2, 0.0f);
    }
}

// ---------------------------------------------------------------------------
// Kernel B: per-batch GraphSAGE x2 + head. (r7 version — measured ~20-26us,
// 4x faster than the original 256-thread scalar-load version)
// ---------------------------------------------------------------------------
__global__ __launch_bounds__(512, 1)
void sage_kernel(const float* __restrict__ nodes, const int* __restrict__ edge,
                 const float* __restrict__ s1l, const float* __restrict__ s1lb,
                 const float* __restrict__ s1r,
                 const float* __restrict__ s2l, const float* __restrict__ s2lb,
                 const float* __restrict__ s2r,
                 const float* __restrict__ ow,  const float* __restrict__ ob,
                 float* __restrict__ out)
{
    __shared__ float nd[N_ * HID];
    __shared__ float agg[N_ * HID];
    __shared__ float g1[N_ * 64];
    __shared__ float agg2[N_ * 64];
    __shared__ float g2[N_ * 32];
    __shared__ float deg[N_];
    __shared__ float invdeg[N_];

    const int t = threadIdx.x;
    const int b = blockIdx.x;
    const int* esrc = edge;
    const int* edst = edge + E_;

    for (int i = t; i < N_ * HID; i += 512) {
        nd[i]  = nodes[(size_t)b * N_ * HID + i];
        agg[i] = 0.0f;
    }
    for (int i = t; i < N_; i += 512) deg[i] = 0.0f;
    __syncthreads();

    if (t < E_) atomicAdd(&deg[edst[t]], 1.0f);
    for (int i = t; i < E_ * HID; i += 512) {
        int e = i / HID, k = i % HID;
        atomicAdd(&agg[edst[e] * HID + k], nd[esrc[e] * HID + k]);
    }
    __syncthreads();
    for (int i = t; i < N_; i += 512) invdeg[i] = 1.0f / fmaxf(deg[i], 1.0f);
    __syncthreads();

    {
        const int i = t >> 3, n0 = t & 7;
        const float4* lr = (const float4*)(s1l + (size_t)i * HID);
        const float4* rr = (const float4*)(s1r + (size_t)i * HID);
        float acc[5], id[5];
        #pragma unroll
        for (int j = 0; j < 5; ++j) {
            acc[j] = s1lb[i];
            id[j]  = invdeg[n0 + 8 * j];
        }
        for (int kq = 0; kq < 25; ++kq) {
            float4 lw = lr[kq], rw = rr[kq];
            #pragma unroll
            for (int j = 0; j < 5; ++j) {
                const int n = n0 + 8 * j;
                float4 ag = *(const float4*)&agg[n * HID + 4 * kq];
                float4 nv = *(const float4*)&nd[n * HID + 4 * kq];
                acc[j] = fmaf(lw.x, ag.x * id[j], acc[j]);
                acc[j] = fmaf(lw.y, ag.y * id[j], acc[j]);
                acc[j] = fmaf(lw.z, ag.z * id[j], acc[j]);
                acc[j] = fmaf(lw.w, ag.w * id[j], acc[j]);
                acc[j] = fmaf(rw.x, nv.x, acc[j]);
                acc[j] = fmaf(rw.y, nv.y, acc[j]);
                acc[j] = fmaf(rw.z, nv.z, acc[j]);
                acc[j] = fmaf(rw.w, nv.w, acc[j]);
            }
        }
        #pragma unroll
        for (int j = 0; j < 5; ++j)
            g1[(n0 + 8 * j) * 64 + i] = fmaxf(acc[j], 0.0f);
    }
    __syncthreads();
    for (int i = t; i < N_ * 64; i += 512) agg2[i] = 0.0f;
    __syncthreads();
    for (int i = t; i < E_ * 64; i += 512) {
        int e = i >> 6, k = i & 63;
        atomicAdd(&agg2[edst[e] * 64 + k], g1[esrc[e] * 64 + k]);
    }
    __syncthreads();

    {
        const int i = t >> 4, n0 = t & 15;
        const float4* lr = (const float4*)(s2l + (size_t)i * 64);
        const float4* rr = (const float4*)(s2r + (size_t)i * 64);
        float acc[3] = {s2lb[i], s2lb[i], s2lb[i]};
        float id[3];
        #pragma unroll
        for (int j = 0; j < 3; ++j) {
            int n = n0 + 16 * j;
            id[j] = (n < N_) ? invdeg[n] : 0.0f;
        }
        for (int kq = 0; kq < 16; ++kq) {
            float4 lw = lr[kq], rw = rr[kq];
            #pragma unroll
            for (int j = 0; j < 3; ++j) {
                const int n = n0 + 16 * j;
                if (n < N_) {
                    float4 ag = *(const float4*)&agg2[n * 64 + 4 * kq];
                    float4 nv = *(const float4*)&g1[n * 64 + 4 * kq];
                    acc[j] = fmaf(lw.x, ag.x * id[j], acc[j]);
                    acc[j] = fmaf(lw.y, ag.y * id[j], acc[j]);
                    acc[j] = fmaf(lw.z, ag.z * id[j], acc[j]);
                    acc[j] = fmaf(lw.w, ag.w * id[j], acc[j]);
                    acc[j] = fmaf(rw.x, nv.x, acc[j]);
                    acc[j] = fmaf(rw.y, nv.y, acc[j]);
                    acc[j] = fmaf(rw.z, nv.z, acc[j]);
                    acc[j] = fmaf(rw.w, nv.w, acc[j]);
                }
            }
        }
        #pragma unroll
        for (int j = 0; j < 3; ++j) {
            int n = n0 + 16 * j;
            if (n < N_) g2[n * 32 + i] = fmaxf(acc[j], 0.0f);
        }
    }
    __syncthreads();

    if (t < N_ * 2) {
        const int n = t >> 1, c = t & 1;
        const float4* wr = (const float4*)(ow + (size_t)c * 32);
        float acc = ob[c];
        for (int kq = 0; kq < 8; ++kq) {
            float4 w4 = wr[kq];
            float4 g4 = *(const float4*)&g2[n * 32 + 4 * kq];
            acc = fmaf(w4.x, g4.x, acc);
            acc = fmaf(w4.y, g4.y, acc);
            acc = fmaf(w4.z, g4.z, acc);
            acc = fmaf(w4.w, g4.w, acc);
        }
        out[((size_t)b * N_ + n) * 2 + c] = fmaxf(acc, 0.0f);
    }
}

extern "C" void kernel_launch(void* const* d_in, const int* in_sizes, int n_in,
                              void* d_out, int out_size, void* d_ws, size_t ws_size,
                              hipStream_t stream) {
    const float* X        = (const float*)d_in[0];
    const float* ts       = (const float*)d_in[1];
    const int*   edge     = (const int*)  d_in[2];
    const float* emb_pos  = (const float*)d_in[3];
    const float* emb_team = (const float*)d_in[4];
    const float* Wall_w   = (const float*)d_in[5];
    const float* Wall_b   = (const float*)d_in[6];
    const float* Uall_w   = (const float*)d_in[7];
    const float* Uall_b   = (const float*)d_in[8];
    const float* Wd_w     = (const float*)d_in[9];
    const float* Wd_b     = (const float*)d_in[10];
    const float* lin_w    = (const float*)d_in[11];
    const float* lin_b    = (const float*)d_in[12];
    const float* s1l      = (const float*)d_in[13];
    const float* s1lb     = (const float*)d_in[14];
    const float* s1r      = (const float*)d_in[15];
    const float* s2l      = (const float*)d_in[16];
    const float* s2lb     = (const float*)d_in[17];
    const float* s2r      = (const float*)d_in[18];
    const float* ow       = (const float*)d_in[19];
    const float* ob       = (const float*)d_in[20];

    float*     nodes = (float*)d_ws;                              // 1,024,000 B
    _Float16*  Wfrag = (_Float16*)((char*)d_ws + 1024000);        // 250*64*8*2 = 256,000 B

    repack_kernel<<<(NU * 64 + 255) / 256, 256, 0, stream>>>(Wall_w, Uall_w, Wd_w,
                                                             Wall_b, Uall_b, Wd_b, Wfrag);

    lstm_kernel<<<NBLK, NTHR, 0, stream>>>(X, ts, emb_pos, emb_team, Wfrag,
                                           lin_w, lin_b, nodes);
    sage_kernel<<<B_, 512, 0, stream>>>(nodes, edge, s1l, s1lb, s1r,
                                        s2l, s2lb, s2r, ow, ob, (float*)d_out);
}

// Round 11
// 247.846 us; speedup vs baseline: 1.7271x; 1.0527x over previous
//
#include <hip/hip_runtime.h>
#include <math.h>

#define B_    64
#define W_    128
#define N_    40
#define FIN   66
#define HID   100
#define NEWD  71
#define MSEQ  10
#define NBLK  256
#define NTHR  1024  // 16 waves: 13 compute + 3 staging
#define E_    240

#define NGU   150   // gate units: 25 tiles * 6 kc
#define NU    250   // + decay-mini units: 25 tiles * 4 kc (rows duplicated x4)

// hx row: 2 parity regions of 192 cols ([0..99]=h [100..170]=xe [171]=1 [172..191]=0)
#define HROW  392
#define CROW  264   // cx row: 2 parity regions of 128 ([0..99]=c [100]=1 [101..127]=0)
#define ROWH(m) ((m)*HROW + (((m)>>3)<<3))
#define ROWC(m) ((m)*CROW + (((m)>>3)<<3))
#define HXSZ  (15*HROW + 8 + HROW)   // 6280
#define CXSZ  (15*CROW + 8 + CROW)   // 4232

typedef float    f32x4 __attribute__((ext_vector_type(4)));
typedef _Float16 f16x4 __attribute__((ext_vector_type(4)));
typedef _Float16 f16x8 __attribute__((ext_vector_type(8)));

__device__ __forceinline__ float rcp_(float x) { return __builtin_amdgcn_rcpf(x); }

// lgkm-only barrier: LDS visibility without draining global prefetch (vmcnt)
#define LBAR() do {                                            \
    asm volatile("s_waitcnt lgkmcnt(0)" ::: "memory");         \
    __builtin_amdgcn_s_barrier();                              \
    asm volatile("" ::: "memory");                             \
} while (0)

// ---------------------------------------------------------------------------
// Repack weights into f16 A-fragments for mfma_f32_16x16x32_f16 (r6 layout,
// validated: absmax 2.44e-4).
// GATE (u<150): rows interleaved R=4*unit+gate -> src row gate*100+unit.
//   k<100: Wall; 100..170: Uall; k==171: Wall_b+Uall_b (bias-as-input); else 0.
// DECAY-MINI (u>=150): row R -> Wd row 4T+(R>>2) (4x duplicated rows).
//   k<100: Wd; k==100: Wd_b; else 0.
// ---------------------------------------------------------------------------
__global__ void repack_kernel(const float* __restrict__ Wall_w,
                              const float* __restrict__ Uall_w,
                              const float* __restrict__ Wd_w,
                              const float* __restrict__ Wall_b,
                              const float* __restrict__ Uall_b,
                              const float* __restrict__ Wd_b,
                              _Float16* __restrict__ Wfrag)
{
    int idx = blockIdx.x * 256 + threadIdx.x;
    if (idx >= NU * 64) return;
    int u = idx >> 6, l = idx & 63;
    f16x8 v;
    #pragma unroll
    for (int e = 0; e < 8; ++e) {
        float wv = 0.0f;
        int k = ((l >> 4) << 3) + e;
        if (u < NGU) {
            int T = u / 6, j = u % 6;
            int R = T * 16 + (l & 15);
            int src = (R & 3) * 100 + (R >> 2);
            k += j * 32;
            if (k < 100)       wv = Wall_w[src * HID + k];
            else if (k < 171)  wv = Uall_w[src * NEWD + (k - 100)];
            else if (k == 171) wv = Wall_b[src] + Uall_b[src];
        } else {
            int du = u - NGU;
            int T = du >> 2, j = du & 3;
            int srcrow = 4 * T + ((l & 15) >> 2);
            k += j * 32;
            if (k < 100)       wv = Wd_w[srcrow * HID + k];
            else if (k == 100) wv = Wd_b[srcrow];
        }
        v[e] = (_Float16)wv;
    }
    *(f16x8*)(Wfrag + (size_t)idx * 8) = v;
}

// ---------------------------------------------------------------------------
// LSTM: 256 blocks x 1024 threads. ONE lgkm barrier per step. (r6 chassis —
// 197us champion — plus: setprio(1) on compute waves, fused-rcp gate math,
// unroll-2 step loop.)
// ---------------------------------------------------------------------------
__global__ __launch_bounds__(NTHR, 4)
void lstm_kernel(const float* __restrict__ X, const float* __restrict__ ts,
                 const float* __restrict__ emb_pos, const float* __restrict__ emb_team,
                 const _Float16* __restrict__ Wfrag,
                 const float* __restrict__ lin_w, const float* __restrict__ lin_b,
                 float* __restrict__ nodes)
{
    __shared__ __align__(16) _Float16 hx[HXSZ];
    __shared__ __align__(16) _Float16 cx[CXSZ];
    __shared__ float ts_s[2][16];

    const int t = threadIdx.x, l = t & 63, wv = t >> 6;
    const int uoff = l >> 4, m = l & 15;
    const int r0 = blockIdx.x * MSEQ;
    const bool comp = (wv < 13);

    // ---- zero LDS ----
    for (int i = t; i < HXSZ; i += NTHR) hx[i] = (_Float16)0.0f;
    for (int i = t; i < CXSZ; i += NTHR) cx[i] = (_Float16)0.0f;
    if (t < 32) ((float*)ts_s)[t] = 0.0f;

    // ---- compute-wave setup ----
    const int tA = 2 * wv;
    const int tB = (2 * wv + 1 < 25) ? (2 * wv + 1) : 24;
    const int uA = 4 * tA + uoff, uB = 4 * tB + uoff;
    f16x8 afA[6], afB[6], adA[4], adB[4];
    if (comp) {
        #pragma unroll
        for (int j = 0; j < 6; ++j) {
            afA[j] = *(const f16x8*)(Wfrag + ((size_t)(tA * 6 + j) * 64 + l) * 8);
            afB[j] = *(const f16x8*)(Wfrag + ((size_t)(tB * 6 + j) * 64 + l) * 8);
        }
        #pragma unroll
        for (int j = 0; j < 4; ++j) {
            adA[j] = *(const f16x8*)(Wfrag + ((size_t)(NGU + tA * 4 + j) * 64 + l) * 8);
            adB[j] = *(const f16x8*)(Wfrag + ((size_t)(NGU + tB * 4 + j) * 64 + l) * 8);
        }
    }
    float cregA = 0.f, cregB = 0.f;

    // ---- staging roles (waves 13..15) ----
    const float* xld = nullptr; int xm = 0, xp = 0;
    const float* xcat = nullptr; int me = 0;
    const float* tsp = nullptr; int mt = 0;
    {
        int s = t - 832;
        if (s >= 0 && s < 160) {
            xm = s >> 4; xp = s & 15;
            int r = r0 + xm, b = r / N_, n = r % N_;
            xld = X + ((size_t)b * W_ * N_ + n) * FIN + 4 * xp;
        } else if (s >= 160 && s < 170) {
            me = s - 160;
            int r = r0 + me, b = r / N_, n = r % N_;
            xcat = X + ((size_t)b * W_ * N_ + n) * FIN;
        } else if (s >= 170 && s < 180) {
            mt = s - 170;
            int r = r0 + mt, b = r / N_, n = r % N_;
            tsp = ts + (size_t)b * W_ * N_ + n;
        }
    }
    __syncthreads();

    // ---- constant-1 bias inputs (both parities) ----
    if (t < 32) {
        int r = t & 15, pp = t >> 4;
        hx[ROWH(r) + pp * 192 + 171] = (_Float16)1.0f;
        cx[ROWC(r) + pp * 128 + 100] = (_Float16)1.0f;
    }
    // ---- stage xe(0)/ts(0) into parity 0 ----
    if (xld) {
        float2 a = *(const float2*)xld;
        float2 b2 = *(const float2*)(xld + 2);
        f16x4 v = {(_Float16)a.x, (_Float16)a.y, (_Float16)b2.x, (_Float16)b2.y};
        *(f16x4*)&hx[ROWH(xm) + 100 + 4 * xp] = v;
    }
    if (xcat) {
        float c0f = xcat[64], c1f = xcat[65];
        int ip = (int)c0f, itm = (int)c1f;
        int sp = ip > 0 ? ip - 1 : 0;   float fp  = ip > 0 ? 1.f : 0.f;
        int st = itm > 0 ? itm - 1 : 0; float ft_ = itm > 0 ? 1.f : 0.f;
        #pragma unroll
        for (int q = 0; q < 4; ++q) hx[ROWH(me) + 164 + q] = (_Float16)(emb_pos[sp * 4 + q] * fp);
        #pragma unroll
        for (int q = 0; q < 3; ++q) hx[ROWH(me) + 168 + q] = (_Float16)(emb_team[st * 3 + q] * ft_);
    }
    if (tsp) ts_s[0][mt] = tsp[0];

    // ---- preload regs for step 1 ----
    float2 pa = {0.f, 0.f}, pb = {0.f, 0.f};
    float pc0 = 0.f, pc1 = 0.f, ptv = 0.f;
    {
        const size_t off1 = (size_t)N_ * FIN;
        if (xld)  { pa = *(const float2*)(xld + off1); pb = *(const float2*)(xld + off1 + 2); }
        if (xcat) { pc0 = xcat[off1 + 64]; pc1 = xcat[off1 + 65]; }
        if (tsp)  ptv = tsp[(size_t)N_];
    }
    __syncthreads();

    const int rowhm = ROWH(m) + (uoff << 3);
    const int rowcm = ROWC(m) + (uoff << 3);
    const int rowhw = ROWH(m);
    const int rowcw = ROWC(m);

    // ---- main loop: ONE barrier per step ----
    #pragma unroll 2
    for (int w = 0; w < W_; ++w) {
        const int p = w & 1, np = p ^ 1;
        if (comp) {
            __builtin_amdgcn_s_setprio(1);
            const int hb = rowhm + p * 192;
            f16x8 bh0 = *(const f16x8*)&hx[hb];
            f16x8 bh1 = *(const f16x8*)&hx[hb + 32];
            f16x8 bh2 = *(const f16x8*)&hx[hb + 64];
            f16x8 bh3 = *(const f16x8*)&hx[hb + 96];
            f16x8 bh4 = *(const f16x8*)&hx[hb + 128];
            f16x8 bh5 = *(const f16x8*)&hx[hb + 160];
            f32x4 aA = {0.f, 0.f, 0.f, 0.f}, aB = {0.f, 0.f, 0.f, 0.f};
            aA = __builtin_amdgcn_mfma_f32_16x16x32_f16(afA[0], bh0, aA, 0, 0, 0);
            aB = __builtin_amdgcn_mfma_f32_16x16x32_f16(afB[0], bh0, aB, 0, 0, 0);
            aA = __builtin_amdgcn_mfma_f32_16x16x32_f16(afA[1], bh1, aA, 0, 0, 0);
            aB = __builtin_amdgcn_mfma_f32_16x16x32_f16(afB[1], bh1, aB, 0, 0, 0);
            aA = __builtin_amdgcn_mfma_f32_16x16x32_f16(afA[2], bh2, aA, 0, 0, 0);
            aB = __builtin_amdgcn_mfma_f32_16x16x32_f16(afB[2], bh2, aB, 0, 0, 0);
            aA = __builtin_amdgcn_mfma_f32_16x16x32_f16(afA[3], bh3, aA, 0, 0, 0);
            aB = __builtin_amdgcn_mfma_f32_16x16x32_f16(afB[3], bh3, aB, 0, 0, 0);
            aA = __builtin_amdgcn_mfma_f32_16x16x32_f16(afA[4], bh4, aA, 0, 0, 0);
            aB = __builtin_amdgcn_mfma_f32_16x16x32_f16(afB[4], bh4, aB, 0, 0, 0);
            aA = __builtin_amdgcn_mfma_f32_16x16x32_f16(afA[5], bh5, aA, 0, 0, 0);
            aB = __builtin_amdgcn_mfma_f32_16x16x32_f16(afB[5], bh5, aB, 0, 0, 0);

            const int cb = rowcm + p * 128;
            f16x8 bc0 = *(const f16x8*)&cx[cb];
            f16x8 bc1 = *(const f16x8*)&cx[cb + 32];
            f16x8 bc2 = *(const f16x8*)&cx[cb + 64];
            f16x8 bc3 = *(const f16x8*)&cx[cb + 96];
            f32x4 dA = {0.f, 0.f, 0.f, 0.f}, dB = {0.f, 0.f, 0.f, 0.f};
            dA = __builtin_amdgcn_mfma_f32_16x16x32_f16(adA[0], bc0, dA, 0, 0, 0);
            dB = __builtin_amdgcn_mfma_f32_16x16x32_f16(adB[0], bc0, dB, 0, 0, 0);
            dA = __builtin_amdgcn_mfma_f32_16x16x32_f16(adA[1], bc1, dA, 0, 0, 0);
            dB = __builtin_amdgcn_mfma_f32_16x16x32_f16(adB[1], bc1, dB, 0, 0, 0);
            dA = __builtin_amdgcn_mfma_f32_16x16x32_f16(adA[2], bc2, dA, 0, 0, 0);
            dB = __builtin_amdgcn_mfma_f32_16x16x32_f16(adB[2], bc2, dB, 0, 0, 0);
            dA = __builtin_amdgcn_mfma_f32_16x16x32_f16(adA[3], bc3, dA, 0, 0, 0);
            dB = __builtin_amdgcn_mfma_f32_16x16x32_f16(adB[3], bc3, dB, 0, 0, 0);

            if (m < MSEQ) {
                const float tsv = ts_s[p][m];
                const float e1 = tsv - 1.0f;
                {
                    // fused-rcp update: f=1/(1+ef); i*ct=1/((1+ei)(1+ec));
                    // cs1=2/(1+ed)-1; o*tanh(cn)=(1-ecn)/((1+eo)(1+ecn))
                    float ef = __expf(-aA[0]);
                    float ei = __expf(-aA[1]);
                    float eo = __expf(-aA[2]);
                    float ec = __expf(-aA[3]);
                    float ed = __expf(-2.0f * dA[0]);
                    float cs1 = fmaf(2.0f, rcp_(1.0f + ed), -1.0f);
                    float fg  = rcp_(1.0f + ef);
                    float ict = rcp_(fmaf(ei, ec, 1.0f + ei + ec));
                    float cn  = fg * fmaf(cs1, e1, cregA) + ict;
                    cregA = cn;
                    float ecn = __expf(-2.0f * cn);
                    float hn  = (1.0f - ecn) * rcp_((1.0f + eo) * (1.0f + ecn));
                    hx[rowhw + np * 192 + uA] = (_Float16)hn;
                    cx[rowcw + np * 128 + uA] = (_Float16)cn;
                }
                {
                    float ef = __expf(-aB[0]);
                    float ei = __expf(-aB[1]);
                    float eo = __expf(-aB[2]);
                    float ec = __expf(-aB[3]);
                    float ed = __expf(-2.0f * dB[0]);
                    float cs1 = fmaf(2.0f, rcp_(1.0f + ed), -1.0f);
                    float fg  = rcp_(1.0f + ef);
                    float ict = rcp_(fmaf(ei, ec, 1.0f + ei + ec));
                    float cn  = fg * fmaf(cs1, e1, cregB) + ict;
                    cregB = cn;
                    float ecn = __expf(-2.0f * cn);
                    float hn  = (1.0f - ecn) * rcp_((1.0f + eo) * (1.0f + ecn));
                    hx[rowhw + np * 192 + uB] = (_Float16)hn;
                    cx[rowcw + np * 128 + uB] = (_Float16)cn;
                }
            }
            __builtin_amdgcn_s_setprio(0);
        } else {
            if (w + 1 < W_) {
                if (xld) {
                    f16x4 v = {(_Float16)pa.x, (_Float16)pa.y, (_Float16)pb.x, (_Float16)pb.y};
                    *(f16x4*)&hx[ROWH(xm) + np * 192 + 100 + 4 * xp] = v;
                }
                if (xcat) {
                    int ip = (int)pc0, itm = (int)pc1;
                    int sp = ip > 0 ? ip - 1 : 0;   float fp  = ip > 0 ? 1.f : 0.f;
                    int st = itm > 0 ? itm - 1 : 0; float ft_ = itm > 0 ? 1.f : 0.f;
                    #pragma unroll
                    for (int q = 0; q < 4; ++q) hx[ROWH(me) + np * 192 + 164 + q] = (_Float16)(emb_pos[sp * 4 + q] * fp);
                    #pragma unroll
                    for (int q = 0; q < 3; ++q) hx[ROWH(me) + np * 192 + 168 + q] = (_Float16)(emb_team[st * 3 + q] * ft_);
                }
                if (tsp) ts_s[np][mt] = ptv;
                if (w + 2 < W_) {
                    const size_t off = (size_t)(w + 2) * (N_ * FIN);
                    if (xld)  { pa = *(const float2*)(xld + off); pb = *(const float2*)(xld + off + 2); }
                    if (xcat) { pc0 = xcat[off + 64]; pc1 = xcat[off + 65]; }
                    if (tsp)  ptv = tsp[(size_t)(w + 2) * N_];
                }
            }
        }
        LBAR();
    }

    // ---- lin head: final h is in parity 0 (written at w=127 -> np=0) ----
    if (t < HID * MSEQ) {
        const int i = t / MSEQ, mm = t % MSEQ;
        const float* lr = lin_w + (size_t)i * HID;
        float acc2 = lin_b[i];
        for (int k = 0; k < HID; ++k)
            acc2 = fmaf(lr[k], (float)hx[ROWH(mm) + k], acc2);
        nodes[(size_t)(r0 + mm) * HID + i] = fmaxf(acc2, 0.0f);
    }
}

// ---------------------------------------------------------------------------
// Kernel B: per-batch GraphSAGE x2 + head. (r7 version — validated fast)
// ---------------------------------------------------------------------------
__global__ __launch_bounds__(512, 1)
void sage_kernel(const float* __restrict__ nodes, const int* __restrict__ edge,
                 const float* __restrict__ s1l, const float* __restrict__ s1lb,
                 const float* __restrict__ s1r,
                 const float* __restrict__ s2l, const float* __restrict__ s2lb,
                 const float* __restrict__ s2r,
                 const float* __restrict__ ow,  const float* __restrict__ ob,
                 float* __restrict__ out)
{
    __shared__ float nd[N_ * HID];
    __shared__ float agg[N_ * HID];
    __shared__ float g1[N_ * 64];
    __shared__ float agg2[N_ * 64];
    __shared__ float g2[N_ * 32];
    __shared__ float deg[N_];
    __shared__ float invdeg[N_];

    const int t = threadIdx.x;
    const int b = blockIdx.x;
    const int* esrc = edge;
    const int* edst = edge + E_;

    for (int i = t; i < N_ * HID; i += 512) {
        nd[i]  = nodes[(size_t)b * N_ * HID + i];
        agg[i] = 0.0f;
    }
    for (int i = t; i < N_; i += 512) deg[i] = 0.0f;
    __syncthreads();

    if (t < E_) atomicAdd(&deg[edst[t]], 1.0f);
    for (int i = t; i < E_ * HID; i += 512) {
        int e = i / HID, k = i % HID;
        atomicAdd(&agg[edst[e] * HID + k], nd[esrc[e] * HID + k]);
    }
    __syncthreads();
    for (int i = t; i < N_; i += 512) invdeg[i] = 1.0f / fmaxf(deg[i], 1.0f);
    __syncthreads();

    {
        const int i = t >> 3, n0 = t & 7;
        const float4* lr = (const float4*)(s1l + (size_t)i * HID);
        const float4* rr = (const float4*)(s1r + (size_t)i * HID);
        float acc[5], id[5];
        #pragma unroll
        for (int j = 0; j < 5; ++j) {
            acc[j] = s1lb[i];
            id[j]  = invdeg[n0 + 8 * j];
        }
        for (int kq = 0; kq < 25; ++kq) {
            float4 lw = lr[kq], rw = rr[kq];
            #pragma unroll
            for (int j = 0; j < 5; ++j) {
                const int n = n0 + 8 * j;
                float4 ag = *(const float4*)&agg[n * HID + 4 * kq];
                float4 nv = *(const float4*)&nd[n * HID + 4 * kq];
                acc[j] = fmaf(lw.x, ag.x * id[j], acc[j]);
                acc[j] = fmaf(lw.y, ag.y * id[j], acc[j]);
                acc[j] = fmaf(lw.z, ag.z * id[j], acc[j]);
                acc[j] = fmaf(lw.w, ag.w * id[j], acc[j]);
                acc[j] = fmaf(rw.x, nv.x, acc[j]);
                acc[j] = fmaf(rw.y, nv.y, acc[j]);
                acc[j] = fmaf(rw.z, nv.z, acc[j]);
                acc[j] = fmaf(rw.w, nv.w, acc[j]);
            }
        }
        #pragma unroll
        for (int j = 0; j < 5; ++j)
            g1[(n0 + 8 * j) * 64 + i] = fmaxf(acc[j], 0.0f);
    }
    __syncthreads();
    for (int i = t; i < N_ * 64; i += 512) agg2[i] = 0.0f;
    __syncthreads();
    for (int i = t; i < E_ * 64; i += 512) {
        int e = i >> 6, k = i & 63;
        atomicAdd(&agg2[edst[e] * 64 + k], g1[esrc[e] * 64 + k]);
    }
    __syncthreads();

    {
        const int i = t >> 4, n0 = t & 15;
        const float4* lr = (const float4*)(s2l + (size_t)i * 64);
        const float4* rr = (const float4*)(s2r + (size_t)i * 64);
        float acc[3] = {s2lb[i], s2lb[i], s2lb[i]};
        float id[3];
        #pragma unroll
        for (int j = 0; j < 3; ++j) {
            int n = n0 + 16 * j;
            id[j] = (n < N_) ? invdeg[n] : 0.0f;
        }
        for (int kq = 0; kq < 16; ++kq) {
            float4 lw = lr[kq], rw = rr[kq];
            #pragma unroll
            for (int j = 0; j < 3; ++j) {
                const int n = n0 + 16 * j;
                if (n < N_) {
                    float4 ag = *(const float4*)&agg2[n * 64 + 4 * kq];
                    float4 nv = *(const float4*)&g1[n * 64 + 4 * kq];
                    acc[j] = fmaf(lw.x, ag.x * id[j], acc[j]);
                    acc[j] = fmaf(lw.y, ag.y * id[j], acc[j]);
                    acc[j] = fmaf(lw.z, ag.z * id[j], acc[j]);
                    acc[j] = fmaf(lw.w, ag.w * id[j], acc[j]);
                    acc[j] = fmaf(rw.x, nv.x, acc[j]);
                    acc[j] = fmaf(rw.y, nv.y, acc[j]);
                    acc[j] = fmaf(rw.z, nv.z, acc[j]);
                    acc[j] = fmaf(rw.w, nv.w, acc[j]);
                }
            }
        }
        #pragma unroll
        for (int j = 0; j < 3; ++j) {
            int n = n0 + 16 * j;
            if (n < N_) g2[n * 32 + i] = fmaxf(acc[j], 0.0f);
        }
    }
    __syncthreads();

    if (t < N_ * 2) {
        const int n = t >> 1, c = t & 1;
        const float4* wr = (const float4*)(ow + (size_t)c * 32);
        float acc = ob[c];
        for (int kq = 0; kq < 8; ++kq) {
            float4 w4 = wr[kq];
            float4 g4 = *(const float4*)&g2[n * 32 + 4 * kq];
            acc = fmaf(w4.x, g4.x, acc);
            acc = fmaf(w4.y, g4.y, acc);
            acc = fmaf(w4.z, g4.z, acc);
            acc = fmaf(w4.w, g4.w, acc);
        }
        out[((size_t)b * N_ + n) * 2 + c] = fmaxf(acc, 0.0f);
    }
}

extern "C" void kernel_launch(void* const* d_in, const int* in_sizes, int n_in,
                              void* d_out, int out_size, void* d_ws, size_t ws_size,
                              hipStream_t stream) {
    const float* X        = (const float*)d_in[0];
    const float* ts       = (const float*)d_in[1];
    const int*   edge     = (const int*)  d_in[2];
    const float* emb_pos  = (const float*)d_in[3];
    const float* emb_team = (const float*)d_in[4];
    const float* Wall_w   = (const float*)d_in[5];
    const float* Wall_b   = (const float*)d_in[6];
    const float* Uall_w   = (const float*)d_in[7];
    const float* Uall_b   = (const float*)d_in[8];
    const float* Wd_w     = (const float*)d_in[9];
    const float* Wd_b     = (const float*)d_in[10];
    const float* lin_w    = (const float*)d_in[11];
    const float* lin_b    = (const float*)d_in[12];
    const float* s1l      = (const float*)d_in[13];
    const float* s1lb     = (const float*)d_in[14];
    const float* s1r      = (const float*)d_in[15];
    const float* s2l      = (const float*)d_in[16];
    const float* s2lb     = (const float*)d_in[17];
    const float* s2r      = (const float*)d_in[18];
    const float* ow       = (const float*)d_in[19];
    const float* ob       = (const float*)d_in[20];

    float*     nodes = (float*)d_ws;                              // 1,024,000 B
    _Float16*  Wfrag = (_Float16*)((char*)d_ws + 1024000);        // 250*64*8*2 = 256,000 B

    repack_kernel<<<(NU * 64 + 255) / 256, 256, 0, stream>>>(Wall_w, Uall_w, Wd_w,
                                                             Wall_b, Uall_b, Wd_b, Wfrag);

    lstm_kernel<<<NBLK, NTHR, 0, stream>>>(X, ts, emb_pos, emb_team, Wfrag,
                                           lin_w, lin_b, nodes);
    sage_kernel<<<B_, 512, 0, stream>>>(nodes, edge, s1l, s1lb, s1r,
                                        s2l, s2lb, s2r, ow, ob, (float*)d_out);
}

// Round 12
// 246.612 us; speedup vs baseline: 1.7357x; 1.0050x over previous
//
#include <hip/hip_runtime.h>
#include <math.h>

#define B_    64
#define W_    128
#define N_    40
#define FIN   66
#define HID   100
#define NEWD  71
#define MSEQ  10
#define NBLK  256
#define NTHR  1024  // 16 waves: 13 compute + 3 staging
#define E_    240

#define NGU   150   // gate units: 25 tiles * 6 kc
#define NU    250   // + decay-mini units: 25 tiles * 4 kc (rows duplicated x4)

// hx row: 2 parity regions of 192 cols ([0..99]=h [100..170]=xe [171]=1 [172..191]=0)
// FLAT stride (r12 A/B: bump removed — rows m and m+8 alias identically = free 2-way)
#define HROW  392
#define CROW  264   // cx row: 2 parity regions of 128 ([0..99]=c [100]=1 [101..127]=0)
#define ROWH(m) ((m)*HROW)
#define ROWC(m) ((m)*CROW)
#define HXSZ  (16*HROW)
#define CXSZ  (16*CROW)

typedef float    f32x4 __attribute__((ext_vector_type(4)));
typedef _Float16 f16x4 __attribute__((ext_vector_type(4)));
typedef _Float16 f16x8 __attribute__((ext_vector_type(8)));

__device__ __forceinline__ float rcp_(float x) { return __builtin_amdgcn_rcpf(x); }

// lgkm-only barrier: LDS visibility without draining global prefetch (vmcnt)
#define LBAR() do {                                            \
    asm volatile("s_waitcnt lgkmcnt(0)" ::: "memory");         \
    __builtin_amdgcn_s_barrier();                              \
    asm volatile("" ::: "memory");                             \
} while (0)

// ---------------------------------------------------------------------------
// Repack weights into f16 A-fragments for mfma_f32_16x16x32_f16 (r6 layout,
// validated: absmax 2.44e-4).
// GATE (u<150): rows interleaved R=4*unit+gate -> src row gate*100+unit.
//   k<100: Wall; 100..170: Uall; k==171: Wall_b+Uall_b (bias-as-input); else 0.
// DECAY-MINI (u>=150): row R -> Wd row 4T+(R>>2) (4x duplicated rows).
//   k<100: Wd; k==100: Wd_b; else 0.
// ---------------------------------------------------------------------------
__global__ void repack_kernel(const float* __restrict__ Wall_w,
                              const float* __restrict__ Uall_w,
                              const float* __restrict__ Wd_w,
                              const float* __restrict__ Wall_b,
                              const float* __restrict__ Uall_b,
                              const float* __restrict__ Wd_b,
                              _Float16* __restrict__ Wfrag)
{
    int idx = blockIdx.x * 256 + threadIdx.x;
    if (idx >= NU * 64) return;
    int u = idx >> 6, l = idx & 63;
    f16x8 v;
    #pragma unroll
    for (int e = 0; e < 8; ++e) {
        float wv = 0.0f;
        int k = ((l >> 4) << 3) + e;
        if (u < NGU) {
            int T = u / 6, j = u % 6;
            int R = T * 16 + (l & 15);
            int src = (R & 3) * 100 + (R >> 2);
            k += j * 32;
            if (k < 100)       wv = Wall_w[src * HID + k];
            else if (k < 171)  wv = Uall_w[src * NEWD + (k - 100)];
            else if (k == 171) wv = Wall_b[src] + Uall_b[src];
        } else {
            int du = u - NGU;
            int T = du >> 2, j = du & 3;
            int srcrow = 4 * T + ((l & 15) >> 2);
            k += j * 32;
            if (k < 100)       wv = Wd_w[srcrow * HID + k];
            else if (k == 100) wv = Wd_b[srcrow];
        }
        v[e] = (_Float16)wv;
    }
    *(f16x8*)(Wfrag + (size_t)idx * 8) = v;
}

// ---------------------------------------------------------------------------
// LSTM: 256 blocks x 1024 threads. ONE lgkm barrier per step. (r11 champion
// chassis: setprio + fused-rcp + unroll-2; r12 delta: flat LDS row stride.)
// ---------------------------------------------------------------------------
__global__ __launch_bounds__(NTHR, 4)
void lstm_kernel(const float* __restrict__ X, const float* __restrict__ ts,
                 const float* __restrict__ emb_pos, const float* __restrict__ emb_team,
                 const _Float16* __restrict__ Wfrag,
                 const float* __restrict__ lin_w, const float* __restrict__ lin_b,
                 float* __restrict__ nodes)
{
    __shared__ __align__(16) _Float16 hx[HXSZ];
    __shared__ __align__(16) _Float16 cx[CXSZ];
    __shared__ float ts_s[2][16];

    const int t = threadIdx.x, l = t & 63, wv = t >> 6;
    const int uoff = l >> 4, m = l & 15;
    const int r0 = blockIdx.x * MSEQ;
    const bool comp = (wv < 13);

    // ---- zero LDS ----
    for (int i = t; i < HXSZ; i += NTHR) hx[i] = (_Float16)0.0f;
    for (int i = t; i < CXSZ; i += NTHR) cx[i] = (_Float16)0.0f;
    if (t < 32) ((float*)ts_s)[t] = 0.0f;

    // ---- compute-wave setup ----
    const int tA = 2 * wv;
    const int tB = (2 * wv + 1 < 25) ? (2 * wv + 1) : 24;
    const int uA = 4 * tA + uoff, uB = 4 * tB + uoff;
    f16x8 afA[6], afB[6], adA[4], adB[4];
    if (comp) {
        #pragma unroll
        for (int j = 0; j < 6; ++j) {
            afA[j] = *(const f16x8*)(Wfrag + ((size_t)(tA * 6 + j) * 64 + l) * 8);
            afB[j] = *(const f16x8*)(Wfrag + ((size_t)(tB * 6 + j) * 64 + l) * 8);
        }
        #pragma unroll
        for (int j = 0; j < 4; ++j) {
            adA[j] = *(const f16x8*)(Wfrag + ((size_t)(NGU + tA * 4 + j) * 64 + l) * 8);
            adB[j] = *(const f16x8*)(Wfrag + ((size_t)(NGU + tB * 4 + j) * 64 + l) * 8);
        }
    }
    float cregA = 0.f, cregB = 0.f;

    // ---- staging roles (waves 13..15) ----
    const float* xld = nullptr; int xm = 0, xp = 0;
    const float* xcat = nullptr; int me = 0;
    const float* tsp = nullptr; int mt = 0;
    {
        int s = t - 832;
        if (s >= 0 && s < 160) {
            xm = s >> 4; xp = s & 15;
            int r = r0 + xm, b = r / N_, n = r % N_;
            xld = X + ((size_t)b * W_ * N_ + n) * FIN + 4 * xp;
        } else if (s >= 160 && s < 170) {
            me = s - 160;
            int r = r0 + me, b = r / N_, n = r % N_;
            xcat = X + ((size_t)b * W_ * N_ + n) * FIN;
        } else if (s >= 170 && s < 180) {
            mt = s - 170;
            int r = r0 + mt, b = r / N_, n = r % N_;
            tsp = ts + (size_t)b * W_ * N_ + n;
        }
    }
    __syncthreads();

    // ---- constant-1 bias inputs (both parities) ----
    if (t < 32) {
        int r = t & 15, pp = t >> 4;
        hx[ROWH(r) + pp * 192 + 171] = (_Float16)1.0f;
        cx[ROWC(r) + pp * 128 + 100] = (_Float16)1.0f;
    }
    // ---- stage xe(0)/ts(0) into parity 0 ----
    if (xld) {
        float2 a = *(const float2*)xld;
        float2 b2 = *(const float2*)(xld + 2);
        f16x4 v = {(_Float16)a.x, (_Float16)a.y, (_Float16)b2.x, (_Float16)b2.y};
        *(f16x4*)&hx[ROWH(xm) + 100 + 4 * xp] = v;
    }
    if (xcat) {
        float c0f = xcat[64], c1f = xcat[65];
        int ip = (int)c0f, itm = (int)c1f;
        int sp = ip > 0 ? ip - 1 : 0;   float fp  = ip > 0 ? 1.f : 0.f;
        int st = itm > 0 ? itm - 1 : 0; float ft_ = itm > 0 ? 1.f : 0.f;
        #pragma unroll
        for (int q = 0; q < 4; ++q) hx[ROWH(me) + 164 + q] = (_Float16)(emb_pos[sp * 4 + q] * fp);
        #pragma unroll
        for (int q = 0; q < 3; ++q) hx[ROWH(me) + 168 + q] = (_Float16)(emb_team[st * 3 + q] * ft_);
    }
    if (tsp) ts_s[0][mt] = tsp[0];

    // ---- preload regs for step 1 ----
    float2 pa = {0.f, 0.f}, pb = {0.f, 0.f};
    float pc0 = 0.f, pc1 = 0.f, ptv = 0.f;
    {
        const size_t off1 = (size_t)N_ * FIN;
        if (xld)  { pa = *(const float2*)(xld + off1); pb = *(const float2*)(xld + off1 + 2); }
        if (xcat) { pc0 = xcat[off1 + 64]; pc1 = xcat[off1 + 65]; }
        if (tsp)  ptv = tsp[(size_t)N_];
    }
    __syncthreads();

    const int rowhm = ROWH(m) + (uoff << 3);
    const int rowcm = ROWC(m) + (uoff << 3);
    const int rowhw = ROWH(m);
    const int rowcw = ROWC(m);

    // ---- main loop: ONE barrier per step ----
    #pragma unroll 2
    for (int w = 0; w < W_; ++w) {
        const int p = w & 1, np = p ^ 1;
        if (comp) {
            __builtin_amdgcn_s_setprio(1);
            const int hb = rowhm + p * 192;
            f16x8 bh0 = *(const f16x8*)&hx[hb];
            f16x8 bh1 = *(const f16x8*)&hx[hb + 32];
            f16x8 bh2 = *(const f16x8*)&hx[hb + 64];
            f16x8 bh3 = *(const f16x8*)&hx[hb + 96];
            f16x8 bh4 = *(const f16x8*)&hx[hb + 128];
            f16x8 bh5 = *(const f16x8*)&hx[hb + 160];
            f32x4 aA = {0.f, 0.f, 0.f, 0.f}, aB = {0.f, 0.f, 0.f, 0.f};
            aA = __builtin_amdgcn_mfma_f32_16x16x32_f16(afA[0], bh0, aA, 0, 0, 0);
            aB = __builtin_amdgcn_mfma_f32_16x16x32_f16(afB[0], bh0, aB, 0, 0, 0);
            aA = __builtin_amdgcn_mfma_f32_16x16x32_f16(afA[1], bh1, aA, 0, 0, 0);
            aB = __builtin_amdgcn_mfma_f32_16x16x32_f16(afB[1], bh1, aB, 0, 0, 0);
            aA = __builtin_amdgcn_mfma_f32_16x16x32_f16(afA[2], bh2, aA, 0, 0, 0);
            aB = __builtin_amdgcn_mfma_f32_16x16x32_f16(afB[2], bh2, aB, 0, 0, 0);
            aA = __builtin_amdgcn_mfma_f32_16x16x32_f16(afA[3], bh3, aA, 0, 0, 0);
            aB = __builtin_amdgcn_mfma_f32_16x16x32_f16(afB[3], bh3, aB, 0, 0, 0);
            aA = __builtin_amdgcn_mfma_f32_16x16x32_f16(afA[4], bh4, aA, 0, 0, 0);
            aB = __builtin_amdgcn_mfma_f32_16x16x32_f16(afB[4], bh4, aB, 0, 0, 0);
            aA = __builtin_amdgcn_mfma_f32_16x16x32_f16(afA[5], bh5, aA, 0, 0, 0);
            aB = __builtin_amdgcn_mfma_f32_16x16x32_f16(afB[5], bh5, aB, 0, 0, 0);

            const int cb = rowcm + p * 128;
            f16x8 bc0 = *(const f16x8*)&cx[cb];
            f16x8 bc1 = *(const f16x8*)&cx[cb + 32];
            f16x8 bc2 = *(const f16x8*)&cx[cb + 64];
            f16x8 bc3 = *(const f16x8*)&cx[cb + 96];
            f32x4 dA = {0.f, 0.f, 0.f, 0.f}, dB = {0.f, 0.f, 0.f, 0.f};
            dA = __builtin_amdgcn_mfma_f32_16x16x32_f16(adA[0], bc0, dA, 0, 0, 0);
            dB = __builtin_amdgcn_mfma_f32_16x16x32_f16(adB[0], bc0, dB, 0, 0, 0);
            dA = __builtin_amdgcn_mfma_f32_16x16x32_f16(adA[1], bc1, dA, 0, 0, 0);
            dB = __builtin_amdgcn_mfma_f32_16x16x32_f16(adB[1], bc1, dB, 0, 0, 0);
            dA = __builtin_amdgcn_mfma_f32_16x16x32_f16(adA[2], bc2, dA, 0, 0, 0);
            dB = __builtin_amdgcn_mfma_f32_16x16x32_f16(adB[2], bc2, dB, 0, 0, 0);
            dA = __builtin_amdgcn_mfma_f32_16x16x32_f16(adA[3], bc3, dA, 0, 0, 0);
            dB = __builtin_amdgcn_mfma_f32_16x16x32_f16(adB[3], bc3, dB, 0, 0, 0);

            if (m < MSEQ) {
                const float tsv = ts_s[p][m];
                const float e1 = tsv - 1.0f;
                {
                    float ef = __expf(-aA[0]);
                    float ei = __expf(-aA[1]);
                    float eo = __expf(-aA[2]);
                    float ec = __expf(-aA[3]);
                    float ed = __expf(-2.0f * dA[0]);
                    float cs1 = fmaf(2.0f, rcp_(1.0f + ed), -1.0f);
                    float fg  = rcp_(1.0f + ef);
                    float ict = rcp_(fmaf(ei, ec, 1.0f + ei + ec));
                    float cn  = fg * fmaf(cs1, e1, cregA) + ict;
                    cregA = cn;
                    float ecn = __expf(-2.0f * cn);
                    float hn  = (1.0f - ecn) * rcp_((1.0f + eo) * (1.0f + ecn));
                    hx[rowhw + np * 192 + uA] = (_Float16)hn;
                    cx[rowcw + np * 128 + uA] = (_Float16)cn;
                }
                {
                    float ef = __expf(-aB[0]);
                    float ei = __expf(-aB[1]);
                    float eo = __expf(-aB[2]);
                    float ec = __expf(-aB[3]);
                    float ed = __expf(-2.0f * dB[0]);
                    float cs1 = fmaf(2.0f, rcp_(1.0f + ed), -1.0f);
                    float fg  = rcp_(1.0f + ef);
                    float ict = rcp_(fmaf(ei, ec, 1.0f + ei + ec));
                    float cn  = fg * fmaf(cs1, e1, cregB) + ict;
                    cregB = cn;
                    float ecn = __expf(-2.0f * cn);
                    float hn  = (1.0f - ecn) * rcp_((1.0f + eo) * (1.0f + ecn));
                    hx[rowhw + np * 192 + uB] = (_Float16)hn;
                    cx[rowcw + np * 128 + uB] = (_Float16)cn;
                }
            }
            __builtin_amdgcn_s_setprio(0);
        } else {
            if (w + 1 < W_) {
                if (xld) {
                    f16x4 v = {(_Float16)pa.x, (_Float16)pa.y, (_Float16)pb.x, (_Float16)pb.y};
                    *(f16x4*)&hx[ROWH(xm) + np * 192 + 100 + 4 * xp] = v;
                }
                if (xcat) {
                    int ip = (int)pc0, itm = (int)pc1;
                    int sp = ip > 0 ? ip - 1 : 0;   float fp  = ip > 0 ? 1.f : 0.f;
                    int st = itm > 0 ? itm - 1 : 0; float ft_ = itm > 0 ? 1.f : 0.f;
                    #pragma unroll
                    for (int q = 0; q < 4; ++q) hx[ROWH(me) + np * 192 + 164 + q] = (_Float16)(emb_pos[sp * 4 + q] * fp);
                    #pragma unroll
                    for (int q = 0; q < 3; ++q) hx[ROWH(me) + np * 192 + 168 + q] = (_Float16)(emb_team[st * 3 + q] * ft_);
                }
                if (tsp) ts_s[np][mt] = ptv;
                if (w + 2 < W_) {
                    const size_t off = (size_t)(w + 2) * (N_ * FIN);
                    if (xld)  { pa = *(const float2*)(xld + off); pb = *(const float2*)(xld + off + 2); }
                    if (xcat) { pc0 = xcat[off + 64]; pc1 = xcat[off + 65]; }
                    if (tsp)  ptv = tsp[(size_t)(w + 2) * N_];
                }
            }
        }
        LBAR();
    }

    // ---- lin head: final h is in parity 0 (written at w=127 -> np=0) ----
    if (t < HID * MSEQ) {
        const int i = t / MSEQ, mm = t % MSEQ;
        const float* lr = lin_w + (size_t)i * HID;
        float acc2 = lin_b[i];
        for (int k = 0; k < HID; ++k)
            acc2 = fmaf(lr[k], (float)hx[ROWH(mm) + k], acc2);
        nodes[(size_t)(r0 + mm) * HID + i] = fmaxf(acc2, 0.0f);
    }
}

// ---------------------------------------------------------------------------
// Kernel B: per-batch GraphSAGE x2 + head. (r7 version — validated fast)
// ---------------------------------------------------------------------------
__global__ __launch_bounds__(512, 1)
void sage_kernel(const float* __restrict__ nodes, const int* __restrict__ edge,
                 const float* __restrict__ s1l, const float* __restrict__ s1lb,
                 const float* __restrict__ s1r,
                 const float* __restrict__ s2l, const float* __restrict__ s2lb,
                 const float* __restrict__ s2r,
                 const float* __restrict__ ow,  const float* __restrict__ ob,
                 float* __restrict__ out)
{
    __shared__ float nd[N_ * HID];
    __shared__ float agg[N_ * HID];
    __shared__ float g1[N_ * 64];
    __shared__ float agg2[N_ * 64];
    __shared__ float g2[N_ * 32];
    __shared__ float deg[N_];
    __shared__ float invdeg[N_];

    const int t = threadIdx.x;
    const int b = blockIdx.x;
    const int* esrc = edge;
    const int* edst = edge + E_;

    for (int i = t; i < N_ * HID; i += 512) {
        nd[i]  = nodes[(size_t)b * N_ * HID + i];
        agg[i] = 0.0f;
    }
    for (int i = t; i < N_; i += 512) deg[i] = 0.0f;
    __syncthreads();

    if (t < E_) atomicAdd(&deg[edst[t]], 1.0f);
    for (int i = t; i < E_ * HID; i += 512) {
        int e = i / HID, k = i % HID;
        atomicAdd(&agg[edst[e] * HID + k], nd[esrc[e] * HID + k]);
    }
    __syncthreads();
    for (int i = t; i < N_; i += 512) invdeg[i] = 1.0f / fmaxf(deg[i], 1.0f);
    __syncthreads();

    {
        const int i = t >> 3, n0 = t & 7;
        const float4* lr = (const float4*)(s1l + (size_t)i * HID);
        const float4* rr = (const float4*)(s1r + (size_t)i * HID);
        float acc[5], id[5];
        #pragma unroll
        for (int j = 0; j < 5; ++j) {
            acc[j] = s1lb[i];
            id[j]  = invdeg[n0 + 8 * j];
        }
        for (int kq = 0; kq < 25; ++kq) {
            float4 lw = lr[kq], rw = rr[kq];
            #pragma unroll
            for (int j = 0; j < 5; ++j) {
                const int n = n0 + 8 * j;
                float4 ag = *(const float4*)&agg[n * HID + 4 * kq];
                float4 nv = *(const float4*)&nd[n * HID + 4 * kq];
                acc[j] = fmaf(lw.x, ag.x * id[j], acc[j]);
                acc[j] = fmaf(lw.y, ag.y * id[j], acc[j]);
                acc[j] = fmaf(lw.z, ag.z * id[j], acc[j]);
                acc[j] = fmaf(lw.w, ag.w * id[j], acc[j]);
                acc[j] = fmaf(rw.x, nv.x, acc[j]);
                acc[j] = fmaf(rw.y, nv.y, acc[j]);
                acc[j] = fmaf(rw.z, nv.z, acc[j]);
                acc[j] = fmaf(rw.w, nv.w, acc[j]);
            }
        }
        #pragma unroll
        for (int j = 0; j < 5; ++j)
            g1[(n0 + 8 * j) * 64 + i] = fmaxf(acc[j], 0.0f);
    }
    __syncthreads();
    for (int i = t; i < N_ * 64; i += 512) agg2[i] = 0.0f;
    __syncthreads();
    for (int i = t; i < E_ * 64; i += 512) {
        int e = i >> 6, k = i & 63;
        atomicAdd(&agg2[edst[e] * 64 + k], g1[esrc[e] * 64 + k]);
    }
    __syncthreads();

    {
        const int i = t >> 4, n0 = t & 15;
        const float4* lr = (const float4*)(s2l + (size_t)i * 64);
        const float4* rr = (const float4*)(s2r + (size_t)i * 64);
        float acc[3] = {s2lb[i], s2lb[i], s2lb[i]};
        float id[3];
        #pragma unroll
        for (int j = 0; j < 3; ++j) {
            int n = n0 + 16 * j;
            id[j] = (n < N_) ? invdeg[n] : 0.0f;
        }
        for (int kq = 0; kq < 16; ++kq) {
            float4 lw = lr[kq], rw = rr[kq];
            #pragma unroll
            for (int j = 0; j < 3; ++j) {
                const int n = n0 + 16 * j;
                if (n < N_) {
                    float4 ag = *(const float4*)&agg2[n * 64 + 4 * kq];
                    float4 nv = *(const float4*)&g1[n * 64 + 4 * kq];
                    acc[j] = fmaf(lw.x, ag.x * id[j], acc[j]);
                    acc[j] = fmaf(lw.y, ag.y * id[j], acc[j]);
                    acc[j] = fmaf(lw.z, ag.z * id[j], acc[j]);
                    acc[j] = fmaf(lw.w, ag.w * id[j], acc[j]);
                    acc[j] = fmaf(rw.x, nv.x, acc[j]);
                    acc[j] = fmaf(rw.y, nv.y, acc[j]);
                    acc[j] = fmaf(rw.z, nv.z, acc[j]);
                    acc[j] = fmaf(rw.w, nv.w, acc[j]);
                }
            }
        }
        #pragma unroll
        for (int j = 0; j < 3; ++j) {
            int n = n0 + 16 * j;
            if (n < N_) g2[n * 32 + i] = fmaxf(acc[j], 0.0f);
        }
    }
    __syncthreads();

    if (t < N_ * 2) {
        const int n = t >> 1, c = t & 1;
        const float4* wr = (const float4*)(ow + (size_t)c * 32);
        float acc = ob[c];
        for (int kq = 0; kq < 8; ++kq) {
            float4 w4 = wr[kq];
            float4 g4 = *(const float4*)&g2[n * 32 + 4 * kq];
            acc = fmaf(w4.x, g4.x, acc);
            acc = fmaf(w4.y, g4.y, acc);
            acc = fmaf(w4.z, g4.z, acc);
            acc = fmaf(w4.w, g4.w, acc);
        }
        out[((size_t)b * N_ + n) * 2 + c] = fmaxf(acc, 0.0f);
    }
}

extern "C" void kernel_launch(void* const* d_in, const int* in_sizes, int n_in,
                              void* d_out, int out_size, void* d_ws, size_t ws_size,
                              hipStream_t stream) {
    const float* X        = (const float*)d_in[0];
    const float* ts       = (const float*)d_in[1];
    const int*   edge     = (const int*)  d_in[2];
    const float* emb_pos  = (const float*)d_in[3];
    const float* emb_team = (const float*)d_in[4];
    const float* Wall_w   = (const float*)d_in[5];
    const float* Wall_b   = (const float*)d_in[6];
    const float* Uall_w   = (const float*)d_in[7];
    const float* Uall_b   = (const float*)d_in[8];
    const float* Wd_w     = (const float*)d_in[9];
    const float* Wd_b     = (const float*)d_in[10];
    const float* lin_w    = (const float*)d_in[11];
    const float* lin_b    = (const float*)d_in[12];
    const float* s1l      = (const float*)d_in[13];
    const float* s1lb     = (const float*)d_in[14];
    const float* s1r      = (const float*)d_in[15];
    const float* s2l      = (const float*)d_in[16];
    const float* s2lb     = (const float*)d_in[17];
    const float* s2r      = (const float*)d_in[18];
    const float* ow       = (const float*)d_in[19];
    const float* ob       = (const float*)d_in[20];

    float*     nodes = (float*)d_ws;                              // 1,024,000 B
    _Float16*  Wfrag = (_Float16*)((char*)d_ws + 1024000);        // 250*64*8*2 = 256,000 B

    repack_kernel<<<(NU * 64 + 255) / 256, 256, 0, stream>>>(Wall_w, Uall_w, Wd_w,
                                                             Wall_b, Uall_b, Wd_b, Wfrag);

    lstm_kernel<<<NBLK, NTHR, 0, stream>>>(X, ts, emb_pos, emb_team, Wfrag,
                                           lin_w, lin_b, nodes);
    sage_kernel<<<B_, 512, 0, stream>>>(nodes, edge, s1l, s1lb, s1r,
                                        s2l, s2lb, s2r, ow, ob, (float*)d_out);
}